// Round 1
// baseline (242.735 us; speedup 1.0000x reference)
//
#include <hip/hip_runtime.h>
#include <hip/hip_bf16.h>

// GraphPosteriorHead: B=32, N=64, D=256
// Pipeline:
//  K0: ctx projections (6x (32,256))       -> ws
//  K1: fused encoders + fi/fj projections  -> fi_dep, fjt_dep, fi_cep, fjt_cep
//  K3: edge logits (fused, no h tensor) + entropy partials -> Wd, Wc, entp
//  K6: gate + combine + W_posterior + expm(trace) per batch -> out, traces
//  K7: acyc reduction -> out[131072]

#define LDS_STRIDE 260   // 256 + 4 pad (keeps float4 alignment, breaks bank patterns)

__device__ __forceinline__ float gelu_f(float x) {
    return 0.5f * x * (1.0f + erff(x * 0.70710678118654752440f));
}
__device__ __forceinline__ float sigmoid_f(float x) {
    return 1.0f / (1.0f + expf(-x));
}
__device__ __forceinline__ float f4c(const float4& v, int k) {
    return k == 0 ? v.x : k == 1 ? v.y : k == 2 ? v.z : v.w;
}

// ---------------- K0: context projections ----------------
// ctxproj[which][b][t] = sum_k ctx[b][k] * W[koff+k][t] (+ bias[t])
// which: 0=dge(+b1), 1=cge(+b1), 2=dep_fi(+dep_b1 folded), 3=dep_fj, 4=cep_fi(+cep_b1), 5=cep_fj
__global__ __launch_bounds__(256) void k0_ctx(
    const float* __restrict__ ds, const float* __restrict__ cc,
    const float* __restrict__ dge_w1, const float* __restrict__ dge_b1,
    const float* __restrict__ cge_w1, const float* __restrict__ cge_b1,
    const float* __restrict__ dep_w1, const float* __restrict__ dep_b1,
    const float* __restrict__ cep_w1, const float* __restrict__ cep_b1,
    float* __restrict__ ctxproj)
{
    const int b = blockIdx.x;
    const int which = blockIdx.y;
    const float* ctx; const float* W; const float* bias;
    switch (which) {
        case 0:  ctx = ds; W = dge_w1 + 256 * 256; bias = dge_b1; break;
        case 1:  ctx = cc; W = cge_w1 + 256 * 256; bias = cge_b1; break;
        case 2:  ctx = ds; W = dep_w1 + 256 * 256; bias = dep_b1; break;
        case 3:  ctx = ds; W = dep_w1 + 768 * 256; bias = nullptr; break;
        case 4:  ctx = cc; W = cep_w1 + 256 * 256; bias = cep_b1; break;
        default: ctx = cc; W = cep_w1 + 768 * 256; bias = nullptr; break;
    }
    __shared__ float sctx[256];
    const int tid = threadIdx.x;
    sctx[tid] = ctx[b * 256 + tid];
    __syncthreads();
    float acc = 0.0f;
    #pragma unroll 2
    for (int k = 0; k < 256; k += 4) {
        float4 c4 = *(const float4*)&sctx[k];
        acc = fmaf(c4.x, W[(k + 0) * 256 + tid], acc);
        acc = fmaf(c4.y, W[(k + 1) * 256 + tid], acc);
        acc = fmaf(c4.z, W[(k + 2) * 256 + tid], acc);
        acc = fmaf(c4.w, W[(k + 3) * 256 + tid], acc);
    }
    if (bias) acc += bias[tid];
    ctxproj[(which * 32 + b) * 256 + tid] = acc;
}

// ---------------- K1: fused encoders + fi/fj ----------------
// Per block: 8 rows of one batch. 256 threads: 64 t-quads x 4 row-groups (2 rows each).
__device__ __forceinline__ void gemm8(const float* __restrict__ src,
                                      const float* __restrict__ W,
                                      int r0, int t0, float acc[2][4])
{
    #pragma unroll
    for (int i = 0; i < 2; ++i)
        #pragma unroll
        for (int j = 0; j < 4; ++j) acc[i][j] = 0.0f;
    #pragma unroll 2
    for (int k = 0; k < 256; k += 4) {
        float4 a0 = *(const float4*)&src[(r0 + 0) * LDS_STRIDE + k];
        float4 a1 = *(const float4*)&src[(r0 + 1) * LDS_STRIDE + k];
        float a0k[4] = {a0.x, a0.y, a0.z, a0.w};
        float a1k[4] = {a1.x, a1.y, a1.z, a1.w};
        #pragma unroll
        for (int kk = 0; kk < 4; ++kk) {
            float4 wv = *(const float4*)&W[(k + kk) * 256 + t0];
            acc[0][0] = fmaf(a0k[kk], wv.x, acc[0][0]);
            acc[0][1] = fmaf(a0k[kk], wv.y, acc[0][1]);
            acc[0][2] = fmaf(a0k[kk], wv.z, acc[0][2]);
            acc[0][3] = fmaf(a0k[kk], wv.w, acc[0][3]);
            acc[1][0] = fmaf(a1k[kk], wv.x, acc[1][0]);
            acc[1][1] = fmaf(a1k[kk], wv.y, acc[1][1]);
            acc[1][2] = fmaf(a1k[kk], wv.z, acc[1][2]);
            acc[1][3] = fmaf(a1k[kk], wv.w, acc[1][3]);
        }
    }
}

__global__ __launch_bounds__(256) void k1_encode(
    const float* __restrict__ ve_g,
    const float* __restrict__ dge_w1, const float* __restrict__ dge_w2, const float* __restrict__ dge_b2,
    const float* __restrict__ cge_w1, const float* __restrict__ cge_w2, const float* __restrict__ cge_b2,
    const float* __restrict__ dep_w1, const float* __restrict__ cep_w1,
    const float* __restrict__ ctxproj,
    float* __restrict__ fi_dep, float* __restrict__ fjt_dep,
    float* __restrict__ fi_cep, float* __restrict__ fjt_cep)
{
    __shared__ float sve[8 * LDS_STRIDE];
    __shared__ float sA[8 * LDS_STRIDE];
    __shared__ float sB[8 * LDS_STRIDE];
    const int tid = threadIdx.x;
    const int b = blockIdx.x >> 3;
    const int chunk = blockIdx.x & 7;
    const int n0 = chunk * 8;

    const float* vsrc = ve_g + (b * 64 + n0) * 256;
    #pragma unroll
    for (int i = 0; i < 8; ++i) {
        int idx = tid + i * 256;
        int r = idx >> 8, k = idx & 255;
        sve[r * LDS_STRIDE + k] = vsrc[idx];
    }
    __syncthreads();

    const int tq = tid & 63;
    const int rg = tid >> 6;
    const int t0 = tq * 4;
    const int r0 = rg * 2;

    float acc[2][4];

    // ---- dge stage1: sve -> sA
    gemm8(sve, dge_w1, r0, t0, acc);
    {
        float4 cpv = *(const float4*)&ctxproj[(0 * 32 + b) * 256 + t0];
        float cps[4] = {cpv.x, cpv.y, cpv.z, cpv.w};
        #pragma unroll
        for (int i = 0; i < 2; ++i) {
            float4 o = { gelu_f(acc[i][0] + cps[0]), gelu_f(acc[i][1] + cps[1]),
                         gelu_f(acc[i][2] + cps[2]), gelu_f(acc[i][3] + cps[3]) };
            *(float4*)&sA[(r0 + i) * LDS_STRIDE + t0] = o;
        }
    }
    __syncthreads();

    // ---- dge stage2: sA -> sB (var_data)
    gemm8(sA, dge_w2, r0, t0, acc);
    {
        float4 b2v = *(const float4*)&dge_b2[t0];
        float bs[4] = {b2v.x, b2v.y, b2v.z, b2v.w};
        #pragma unroll
        for (int i = 0; i < 2; ++i) {
            float4 o = { gelu_f(acc[i][0] + bs[0]), gelu_f(acc[i][1] + bs[1]),
                         gelu_f(acc[i][2] + bs[2]), gelu_f(acc[i][3] + bs[3]) };
            *(float4*)&sB[(r0 + i) * LDS_STRIDE + t0] = o;
        }
    }
    __syncthreads();

    // ---- dep fi: sB -> global (ctxproj2 includes dep_b1)
    gemm8(sB, dep_w1, r0, t0, acc);
    {
        float4 cpv = *(const float4*)&ctxproj[(2 * 32 + b) * 256 + t0];
        #pragma unroll
        for (int i = 0; i < 2; ++i) {
            float4 o = { acc[i][0] + cpv.x, acc[i][1] + cpv.y, acc[i][2] + cpv.z, acc[i][3] + cpv.w };
            *(float4*)&fi_dep[(b * 64 + n0 + r0 + i) * 256 + t0] = o;
        }
    }
    // ---- dep fj: sB -> sA
    gemm8(sB, dep_w1 + 512 * 256, r0, t0, acc);
    {
        float4 cpv = *(const float4*)&ctxproj[(3 * 32 + b) * 256 + t0];
        #pragma unroll
        for (int i = 0; i < 2; ++i) {
            float4 o = { acc[i][0] + cpv.x, acc[i][1] + cpv.y, acc[i][2] + cpv.z, acc[i][3] + cpv.w };
            *(float4*)&sA[(r0 + i) * LDS_STRIDE + t0] = o;
        }
    }
    __syncthreads();
    // transposed write fjt_dep[b][t][n0+r]
    {
        float v[8];
        #pragma unroll
        for (int r = 0; r < 8; ++r) v[r] = sA[r * LDS_STRIDE + tid];
        float4 lo = {v[0], v[1], v[2], v[3]};
        float4 hi = {v[4], v[5], v[6], v[7]};
        float* dst = fjt_dep + (b * 256 + tid) * 64 + n0;
        *(float4*)&dst[0] = lo;
        *(float4*)&dst[4] = hi;
    }

    // ---- cge stage1: sve -> sB
    gemm8(sve, cge_w1, r0, t0, acc);
    {
        float4 cpv = *(const float4*)&ctxproj[(1 * 32 + b) * 256 + t0];
        float cps[4] = {cpv.x, cpv.y, cpv.z, cpv.w};
        #pragma unroll
        for (int i = 0; i < 2; ++i) {
            float4 o = { gelu_f(acc[i][0] + cps[0]), gelu_f(acc[i][1] + cps[1]),
                         gelu_f(acc[i][2] + cps[2]), gelu_f(acc[i][3] + cps[3]) };
            *(float4*)&sB[(r0 + i) * LDS_STRIDE + t0] = o;
        }
    }
    __syncthreads();

    // ---- cge stage2: sB -> sA (var_claim)
    gemm8(sB, cge_w2, r0, t0, acc);
    {
        float4 b2v = *(const float4*)&cge_b2[t0];
        float bs[4] = {b2v.x, b2v.y, b2v.z, b2v.w};
        #pragma unroll
        for (int i = 0; i < 2; ++i) {
            float4 o = { gelu_f(acc[i][0] + bs[0]), gelu_f(acc[i][1] + bs[1]),
                         gelu_f(acc[i][2] + bs[2]), gelu_f(acc[i][3] + bs[3]) };
            *(float4*)&sA[(r0 + i) * LDS_STRIDE + t0] = o;
        }
    }
    __syncthreads();

    // ---- cep fi: sA -> global (ctxproj4 includes cep_b1)
    gemm8(sA, cep_w1, r0, t0, acc);
    {
        float4 cpv = *(const float4*)&ctxproj[(4 * 32 + b) * 256 + t0];
        #pragma unroll
        for (int i = 0; i < 2; ++i) {
            float4 o = { acc[i][0] + cpv.x, acc[i][1] + cpv.y, acc[i][2] + cpv.z, acc[i][3] + cpv.w };
            *(float4*)&fi_cep[(b * 64 + n0 + r0 + i) * 256 + t0] = o;
        }
    }
    // ---- cep fj: sA -> sB
    gemm8(sA, cep_w1 + 512 * 256, r0, t0, acc);
    {
        float4 cpv = *(const float4*)&ctxproj[(5 * 32 + b) * 256 + t0];
        #pragma unroll
        for (int i = 0; i < 2; ++i) {
            float4 o = { acc[i][0] + cpv.x, acc[i][1] + cpv.y, acc[i][2] + cpv.z, acc[i][3] + cpv.w };
            *(float4*)&sB[(r0 + i) * LDS_STRIDE + t0] = o;
        }
    }
    __syncthreads();
    {
        float v[8];
        #pragma unroll
        for (int r = 0; r < 8; ++r) v[r] = sB[r * LDS_STRIDE + tid];
        float4 lo = {v[0], v[1], v[2], v[3]};
        float4 hi = {v[4], v[5], v[6], v[7]};
        float* dst = fjt_cep + (b * 256 + tid) * 64 + n0;
        *(float4*)&dst[0] = lo;
        *(float4*)&dst[4] = hi;
    }
}

// ---------------- K3: fused edge logits + entropy partials ----------------
// grid 2048 = (b, i); block 64 = j. fi already includes ctx-proj + b1.
__global__ __launch_bounds__(64) void k3_edges(
    const float* __restrict__ fi_dep, const float* __restrict__ fjt_dep,
    const float* __restrict__ fi_cep, const float* __restrict__ fjt_cep,
    const float* __restrict__ dep_w2, const float* __restrict__ dep_b2,
    const float* __restrict__ cep_w2, const float* __restrict__ cep_b2,
    float* __restrict__ Wd, float* __restrict__ Wc, float* __restrict__ entp)
{
    const int b = blockIdx.x >> 6;
    const int i = blockIdx.x & 63;
    const int j = threadIdx.x;

    const float4* fiD = (const float4*)(fi_dep + (b * 64 + i) * 256);
    const float4* fiC = (const float4*)(fi_cep + (b * 64 + i) * 256);
    const float*  fjD = fjt_dep + b * 256 * 64 + j;
    const float*  fjC = fjt_cep + b * 256 * 64 + j;
    const float4* w2D = (const float4*)dep_w2;
    const float4* w2C = (const float4*)cep_w2;

    float accD = 0.0f, accC = 0.0f;
    #pragma unroll 2
    for (int m = 0; m < 64; ++m) {
        float4 fd = fiD[m];
        float4 wd = w2D[m];
        int d0 = 4 * m;
        float g0 = fjD[(d0 + 0) * 64];
        float g1 = fjD[(d0 + 1) * 64];
        float g2 = fjD[(d0 + 2) * 64];
        float g3 = fjD[(d0 + 3) * 64];
        accD = fmaf(gelu_f(fd.x + g0), wd.x, accD);
        accD = fmaf(gelu_f(fd.y + g1), wd.y, accD);
        accD = fmaf(gelu_f(fd.z + g2), wd.z, accD);
        accD = fmaf(gelu_f(fd.w + g3), wd.w, accD);

        float4 fc = fiC[m];
        float4 wc = w2C[m];
        float h0 = fjC[(d0 + 0) * 64];
        float h1 = fjC[(d0 + 1) * 64];
        float h2 = fjC[(d0 + 2) * 64];
        float h3 = fjC[(d0 + 3) * 64];
        accC = fmaf(gelu_f(fc.x + h0), wc.x, accC);
        accC = fmaf(gelu_f(fc.y + h1), wc.y, accC);
        accC = fmaf(gelu_f(fc.z + h2), wc.z, accC);
        accC = fmaf(gelu_f(fc.w + h3), wc.w, accC);
    }
    float lD = accD + dep_b2[0];
    float lC = accC + cep_b2[0];
    if (j == i) { lD = -1e9f; lC = -1e9f; }
    Wd[(b * 64 + i) * 64 + j] = lD;
    Wc[(b * 64 + i) * 64 + j] = lC;

    // entropy of sigmoid(data logits)
    float p = sigmoid_f(lD);
    float e = -(p * logf(p + 1e-8f) + (1.0f - p) * logf(1.0f - p + 1e-8f));
    #pragma unroll
    for (int off = 32; off; off >>= 1) e += __shfl_down(e, off);
    if (j == 0) entp[b * 64 + i] = e;
}

// ---------------- K6: gate + combine + expm ----------------
// one block per batch; 256 threads
__global__ __launch_bounds__(256) void k6_gate_expm(
    const float* __restrict__ Wd, const float* __restrict__ Wc,
    const float* __restrict__ entp,
    const float* __restrict__ gw1, const float* __restrict__ gb1,
    const float* __restrict__ gw2, const float* __restrict__ gb2,
    const int* __restrict__ n_samples,
    float* __restrict__ out, float* __restrict__ traces)
{
    __shared__ float Xs[64 * 68];
    __shared__ float Rs[64 * 68];
    __shared__ float sgate;
    __shared__ float sent;
    __shared__ int ssexp;

    const int b = blockIdx.x;
    const int tid = threadIdx.x;

    if (tid == 0) {
        float s = 0.0f;
        for (int c = 0; c < 64; ++c) s += entp[b * 64 + c];
        sent = s / 4096.0f;
    }
    __syncthreads();
    if (tid < 64) {
        float ns = fminf((float)n_samples[0] / 1000.0f, 1.0f);
        float ccf = 0.5f;
        float pre = ns * gw1[tid] + ccf * gw1[64 + tid] + sent * gw1[128 + tid] + gb1[tid];
        float hid = gelu_f(pre) * gw2[tid];
        #pragma unroll
        for (int off = 32; off; off >>= 1) hid += __shfl_down(hid, off);
        if (tid == 0) sgate = sigmoid_f(hid + gb2[0]);
    }
    __syncthreads();
    const float g = sgate;

    // combine + write W_posterior + build A = Wsig^2 in LDS
    for (int idx = tid; idx < 4096; idx += 256) {
        float d = Wd[b * 4096 + idx];
        float c = Wc[b * 4096 + idx];
        float post = g * d + (1.0f - g) * c;
        float s = sigmoid_f(post);
        out[b * 4096 + idx] = s;
        int ii = idx >> 6, jj = idx & 63;
        Xs[ii * 68 + jj] = s * s;
    }
    __syncthreads();

    // 1-norm (max column sum; entries >= 0)
    if (tid < 64) {
        float cs = 0.0f;
        for (int r = 0; r < 64; ++r) cs += Xs[r * 68 + tid];
        #pragma unroll
        for (int off = 32; off; off >>= 1) cs = fmaxf(cs, __shfl_down(cs, off));
        if (tid == 0) {
            int se = 0;
            if (cs > 0.5f) se = (int)ceilf(log2f(cs * 2.0f));
            if (se < 0) se = 0;
            if (se > 12) se = 12;
            ssexp = se;
        }
    }
    __syncthreads();
    const int sexp = ssexp;
    const float scale = ldexpf(1.0f, -sexp);
    for (int idx = tid; idx < 4096; idx += 256) {
        Xs[(idx >> 6) * 68 + (idx & 63)] *= scale;
    }
    __syncthreads();

    // R = I + X/14
    for (int idx = tid; idx < 4096; idx += 256) {
        int ii = idx >> 6, jj = idx & 63;
        Rs[ii * 68 + jj] = Xs[ii * 68 + jj] * (1.0f / 14.0f) + ((ii == jj) ? 1.0f : 0.0f);
    }
    __syncthreads();

    const int rq = tid >> 4, cq = tid & 15;
    const int r0 = rq * 4, c0 = cq * 4;

    // Horner: for k=13..1: R = I + (X*R)/k
    for (int k = 13; k >= 1; --k) {
        float acc[4][4];
        #pragma unroll
        for (int i = 0; i < 4; ++i)
            #pragma unroll
            for (int j = 0; j < 4; ++j) acc[i][j] = 0.0f;
        for (int kb = 0; kb < 64; kb += 4) {
            float4 xa[4];
            #pragma unroll
            for (int i = 0; i < 4; ++i) xa[i] = *(const float4*)&Xs[(r0 + i) * 68 + kb];
            #pragma unroll
            for (int kk = 0; kk < 4; ++kk) {
                float4 rv = *(const float4*)&Rs[(kb + kk) * 68 + c0];
                float rj[4] = {rv.x, rv.y, rv.z, rv.w};
                #pragma unroll
                for (int i = 0; i < 4; ++i) {
                    float xv = f4c(xa[i], kk);
                    #pragma unroll
                    for (int j = 0; j < 4; ++j) acc[i][j] = fmaf(xv, rj[j], acc[i][j]);
                }
            }
        }
        __syncthreads();
        float invk = 1.0f / (float)k;
        #pragma unroll
        for (int i = 0; i < 4; ++i)
            #pragma unroll
            for (int j = 0; j < 4; ++j)
                Rs[(r0 + i) * 68 + c0 + j] = acc[i][j] * invk + (((r0 + i) == (c0 + j)) ? 1.0f : 0.0f);
        __syncthreads();
    }

    // squarings with fp64 accumulation
    for (int sq = 0; sq < sexp; ++sq) {
        double acc[4][4];
        #pragma unroll
        for (int i = 0; i < 4; ++i)
            #pragma unroll
            for (int j = 0; j < 4; ++j) acc[i][j] = 0.0;
        for (int kb = 0; kb < 64; kb += 4) {
            float4 xa[4];
            #pragma unroll
            for (int i = 0; i < 4; ++i) xa[i] = *(const float4*)&Rs[(r0 + i) * 68 + kb];
            #pragma unroll
            for (int kk = 0; kk < 4; ++kk) {
                float4 rv = *(const float4*)&Rs[(kb + kk) * 68 + c0];
                double rj[4] = {(double)rv.x, (double)rv.y, (double)rv.z, (double)rv.w};
                #pragma unroll
                for (int i = 0; i < 4; ++i) {
                    double xv = (double)f4c(xa[i], kk);
                    #pragma unroll
                    for (int j = 0; j < 4; ++j) acc[i][j] = fma(xv, rj[j], acc[i][j]);
                }
            }
        }
        __syncthreads();
        #pragma unroll
        for (int i = 0; i < 4; ++i)
            #pragma unroll
            for (int j = 0; j < 4; ++j)
                Rs[(r0 + i) * 68 + c0 + j] = (float)acc[i][j];
        __syncthreads();
    }

    if (tid == 0) {
        double tr = 0.0;
        for (int i = 0; i < 64; ++i) tr += (double)Rs[i * 68 + i];
        traces[b] = (float)tr;
    }
}

// ---------------- K7: acyc ----------------
__global__ void k7_acyc(const float* __restrict__ traces, float* __restrict__ out)
{
    if (threadIdx.x == 0 && blockIdx.x == 0) {
        double s = 0.0;
        for (int b = 0; b < 32; ++b) s += (double)traces[b];
        out[131072] = (float)(s / 32.0 - 64.0);
    }
}

extern "C" void kernel_launch(void* const* d_in, const int* in_sizes, int n_in,
                              void* d_out, int out_size, void* d_ws, size_t ws_size,
                              hipStream_t stream)
{
    (void)in_sizes; (void)n_in; (void)out_size; (void)ws_size;

    const float* ds     = (const float*)d_in[0];
    const float* ve     = (const float*)d_in[1];
    const float* cc     = (const float*)d_in[2];
    const float* dge_w1 = (const float*)d_in[3];
    const float* dge_b1 = (const float*)d_in[4];
    const float* dge_w2 = (const float*)d_in[5];
    const float* dge_b2 = (const float*)d_in[6];
    const float* cge_w1 = (const float*)d_in[7];
    const float* cge_b1 = (const float*)d_in[8];
    const float* cge_w2 = (const float*)d_in[9];
    const float* cge_b2 = (const float*)d_in[10];
    const float* dep_w1 = (const float*)d_in[11];
    const float* dep_b1 = (const float*)d_in[12];
    const float* dep_w2 = (const float*)d_in[13];
    const float* dep_b2 = (const float*)d_in[14];
    const float* cep_w1 = (const float*)d_in[15];
    const float* cep_b1 = (const float*)d_in[16];
    const float* cep_w2 = (const float*)d_in[17];
    const float* cep_b2 = (const float*)d_in[18];
    const float* gw1    = (const float*)d_in[19];
    const float* gb1    = (const float*)d_in[20];
    const float* gw2    = (const float*)d_in[21];
    const float* gb2    = (const float*)d_in[22];
    const int*   nsamp  = (const int*)d_in[23];

    float* ws = (float*)d_ws;
    float* ctxproj = ws;                       // 6*32*256   = 49152
    float* fi_dep  = ctxproj + 49152;          // 32*64*256  = 524288
    float* fjt_dep = fi_dep + 524288;          // 32*256*64  = 524288
    float* fi_cep  = fjt_dep + 524288;         // 524288
    float* fjt_cep = fi_cep + 524288;          // 524288
    float* Wd      = fjt_cep + 524288;         // 32*64*64   = 131072
    float* Wc      = Wd + 131072;              // 131072
    float* entp    = Wc + 131072;              // 32*64      = 2048
    float* traces  = entp + 2048;              // 32

    float* outp = (float*)d_out;

    k0_ctx<<<dim3(32, 6), 256, 0, stream>>>(ds, cc, dge_w1, dge_b1, cge_w1, cge_b1,
                                            dep_w1, dep_b1, cep_w1, cep_b1, ctxproj);
    k1_encode<<<256, 256, 0, stream>>>(ve, dge_w1, dge_w2, dge_b2,
                                       cge_w1, cge_w2, cge_b2,
                                       dep_w1, cep_w1, ctxproj,
                                       fi_dep, fjt_dep, fi_cep, fjt_cep);
    k3_edges<<<2048, 64, 0, stream>>>(fi_dep, fjt_dep, fi_cep, fjt_cep,
                                      dep_w2, dep_b2, cep_w2, cep_b2,
                                      Wd, Wc, entp);
    k6_gate_expm<<<32, 256, 0, stream>>>(Wd, Wc, entp, gw1, gb1, gw2, gb2,
                                         nsamp, outp, traces);
    k7_acyc<<<1, 64, 0, stream>>>(traces, outp);
}

// Round 2
// 173.827 us; speedup vs baseline: 1.3964x; 1.3964x over previous
//
#include <hip/hip_runtime.h>
#include <hip/hip_bf16.h>

// GraphPosteriorHead: B=32, N=64, D=256
// Pipeline:
//  K0: ctx projections (6x (32,256))       -> ws
//  K1: fused encoders + fi/fj projections  -> fi_dep, fjt_dep, fi_cep, fjt_cep
//      (512 thr, 8 waves, k-split-8 per GEMM stage, LDS partial reduction)
//  K3: edge logits (fused, no h tensor) + entropy partials -> Wd, Wc, entp
//  K6: gate + combine + W_posterior + expm(trace) per batch -> out, traces
//  K7: acyc reduction -> out[131072]

#define LDS_STRIDE 260   // 256 + 4 pad

__device__ __forceinline__ float gelu_f(float x) {
    return 0.5f * x * (1.0f + erff(x * 0.70710678118654752440f));
}
__device__ __forceinline__ float sigmoid_f(float x) {
    return 1.0f / (1.0f + expf(-x));
}
__device__ __forceinline__ float f4c(const float4& v, int k) {
    return k == 0 ? v.x : k == 1 ? v.y : k == 2 ? v.z : v.w;
}

// ---------------- K0: context projections ----------------
__global__ __launch_bounds__(256) void k0_ctx(
    const float* __restrict__ ds, const float* __restrict__ cc,
    const float* __restrict__ dge_w1, const float* __restrict__ dge_b1,
    const float* __restrict__ cge_w1, const float* __restrict__ cge_b1,
    const float* __restrict__ dep_w1, const float* __restrict__ dep_b1,
    const float* __restrict__ cep_w1, const float* __restrict__ cep_b1,
    float* __restrict__ ctxproj)
{
    const int b = blockIdx.x;
    const int which = blockIdx.y;
    const float* ctx; const float* W; const float* bias;
    switch (which) {
        case 0:  ctx = ds; W = dge_w1 + 256 * 256; bias = dge_b1; break;
        case 1:  ctx = cc; W = cge_w1 + 256 * 256; bias = cge_b1; break;
        case 2:  ctx = ds; W = dep_w1 + 256 * 256; bias = dep_b1; break;
        case 3:  ctx = ds; W = dep_w1 + 768 * 256; bias = nullptr; break;
        case 4:  ctx = cc; W = cep_w1 + 256 * 256; bias = cep_b1; break;
        default: ctx = cc; W = cep_w1 + 768 * 256; bias = nullptr; break;
    }
    __shared__ float sctx[256];
    const int tid = threadIdx.x;
    sctx[tid] = ctx[b * 256 + tid];
    __syncthreads();
    float acc = 0.0f;
    #pragma unroll 2
    for (int k = 0; k < 256; k += 4) {
        float4 c4 = *(const float4*)&sctx[k];
        acc = fmaf(c4.x, W[(k + 0) * 256 + tid], acc);
        acc = fmaf(c4.y, W[(k + 1) * 256 + tid], acc);
        acc = fmaf(c4.z, W[(k + 2) * 256 + tid], acc);
        acc = fmaf(c4.w, W[(k + 3) * 256 + tid], acc);
    }
    if (bias) acc += bias[tid];
    ctxproj[(which * 32 + b) * 256 + tid] = acc;
}

// ---------------- K1: fused encoders, k-split across 8 waves ----------------
// Each wave: all 8 rows x its 4-col slice per lane, K-slice of 32.
__device__ __forceinline__ void gemm_ks(const float* __restrict__ src,  // LDS [8][LDS_STRIDE]
                                        const float* __restrict__ W,    // global [256][256]
                                        int ks0, int t0, float acc[8][4])
{
    #pragma unroll
    for (int r = 0; r < 8; ++r)
        #pragma unroll
        for (int c = 0; c < 4; ++c) acc[r][c] = 0.0f;
    #pragma unroll 2
    for (int k = ks0; k < ks0 + 32; k += 4) {
        float4 wv0 = *(const float4*)&W[(k + 0) * 256 + t0];
        float4 wv1 = *(const float4*)&W[(k + 1) * 256 + t0];
        float4 wv2 = *(const float4*)&W[(k + 2) * 256 + t0];
        float4 wv3 = *(const float4*)&W[(k + 3) * 256 + t0];
        float4 a[8];
        #pragma unroll
        for (int r = 0; r < 8; ++r) a[r] = *(const float4*)&src[r * LDS_STRIDE + k];
        float4 wvs[4] = {wv0, wv1, wv2, wv3};
        #pragma unroll
        for (int kk = 0; kk < 4; ++kk) {
            float4 wv = wvs[kk];
            #pragma unroll
            for (int r = 0; r < 8; ++r) {
                float av = f4c(a[r], kk);
                acc[r][0] = fmaf(av, wv.x, acc[r][0]);
                acc[r][1] = fmaf(av, wv.y, acc[r][1]);
                acc[r][2] = fmaf(av, wv.z, acc[r][2]);
                acc[r][3] = fmaf(av, wv.w, acc[r][3]);
            }
        }
    }
}

__device__ __forceinline__ void write_part(float* __restrict__ part, int w, int t0,
                                           const float acc[8][4])
{
    #pragma unroll
    for (int r = 0; r < 8; ++r) {
        float4 o = {acc[r][0], acc[r][1], acc[r][2], acc[r][3]};
        *(float4*)&part[(w * 8 + r) * 256 + t0] = o;
    }
}

__device__ __forceinline__ float4 reduce_part(const float* __restrict__ part, int r, int t0)
{
    float4 s = {0.0f, 0.0f, 0.0f, 0.0f};
    #pragma unroll
    for (int w = 0; w < 8; ++w) {
        float4 v = *(const float4*)&part[(w * 8 + r) * 256 + t0];
        s.x += v.x; s.y += v.y; s.z += v.z; s.w += v.w;
    }
    return s;
}

__global__ __launch_bounds__(512) void k1_encode(
    const float* __restrict__ ve_g,
    const float* __restrict__ dge_w1, const float* __restrict__ dge_w2, const float* __restrict__ dge_b2,
    const float* __restrict__ cge_w1, const float* __restrict__ cge_w2, const float* __restrict__ cge_b2,
    const float* __restrict__ dep_w1, const float* __restrict__ cep_w1,
    const float* __restrict__ ctxproj,
    float* __restrict__ fi_dep, float* __restrict__ fjt_dep,
    float* __restrict__ fi_cep, float* __restrict__ fjt_cep)
{
    __shared__ float sve[8 * LDS_STRIDE];
    __shared__ float sA[8 * LDS_STRIDE];
    __shared__ float sB[8 * LDS_STRIDE];
    __shared__ float part[8 * 8 * 256];   // 64 KB partials

    const int tid = threadIdx.x;
    const int b = blockIdx.x >> 3;
    const int chunk = blockIdx.x & 7;
    const int n0 = chunk * 8;

    const int w  = tid >> 6;          // wave id 0..7 (also reduction row id)
    const int t0 = (tid & 63) * 4;    // 4-col slice
    const int ks0 = w * 32;           // k-slice

    // stage ve rows into LDS (512 thr x 1 float4)
    {
        int idx = tid * 4;
        int r = idx >> 8, k = idx & 255;
        *(float4*)&sve[r * LDS_STRIDE + k] = *(const float4*)&ve_g[(b * 64 + n0) * 256 + idx];
    }
    __syncthreads();

    float acc[8][4];

    // ---- 1. dge stage1: sve -> sA
    gemm_ks(sve, dge_w1, ks0, t0, acc);
    write_part(part, w, t0, acc);
    __syncthreads();
    {
        float4 s = reduce_part(part, w, t0);
        float4 cp = *(const float4*)&ctxproj[(0 * 32 + b) * 256 + t0];
        float4 o = {gelu_f(s.x + cp.x), gelu_f(s.y + cp.y), gelu_f(s.z + cp.z), gelu_f(s.w + cp.w)};
        *(float4*)&sA[w * LDS_STRIDE + t0] = o;
    }
    __syncthreads();

    // ---- 2. dge stage2: sA -> sB (var_data)
    gemm_ks(sA, dge_w2, ks0, t0, acc);
    write_part(part, w, t0, acc);
    __syncthreads();
    {
        float4 s = reduce_part(part, w, t0);
        float4 bv = *(const float4*)&dge_b2[t0];
        float4 o = {gelu_f(s.x + bv.x), gelu_f(s.y + bv.y), gelu_f(s.z + bv.z), gelu_f(s.w + bv.w)};
        *(float4*)&sB[w * LDS_STRIDE + t0] = o;
    }
    __syncthreads();

    // ---- 3. dep fi: sB -> global
    gemm_ks(sB, dep_w1, ks0, t0, acc);
    write_part(part, w, t0, acc);
    __syncthreads();
    {
        float4 s = reduce_part(part, w, t0);
        float4 cp = *(const float4*)&ctxproj[(2 * 32 + b) * 256 + t0];
        float4 o = {s.x + cp.x, s.y + cp.y, s.z + cp.z, s.w + cp.w};
        *(float4*)&fi_dep[(b * 64 + n0 + w) * 256 + t0] = o;
    }
    __syncthreads();

    // ---- 4. dep fj: sB -> sA, then transpose to fjt_dep
    gemm_ks(sB, dep_w1 + 512 * 256, ks0, t0, acc);
    write_part(part, w, t0, acc);
    __syncthreads();
    {
        float4 s = reduce_part(part, w, t0);
        float4 cp = *(const float4*)&ctxproj[(3 * 32 + b) * 256 + t0];
        float4 o = {s.x + cp.x, s.y + cp.y, s.z + cp.z, s.w + cp.w};
        *(float4*)&sA[w * LDS_STRIDE + t0] = o;
    }
    __syncthreads();
    {
        int t = tid & 255, half = tid >> 8;
        float v0 = sA[(half * 4 + 0) * LDS_STRIDE + t];
        float v1 = sA[(half * 4 + 1) * LDS_STRIDE + t];
        float v2 = sA[(half * 4 + 2) * LDS_STRIDE + t];
        float v3 = sA[(half * 4 + 3) * LDS_STRIDE + t];
        float4 o = {v0, v1, v2, v3};
        *(float4*)&fjt_dep[(b * 256 + t) * 64 + n0 + half * 4] = o;
    }

    // ---- 5. cge stage1: sve -> sB
    gemm_ks(sve, cge_w1, ks0, t0, acc);
    write_part(part, w, t0, acc);
    __syncthreads();
    {
        float4 s = reduce_part(part, w, t0);
        float4 cp = *(const float4*)&ctxproj[(1 * 32 + b) * 256 + t0];
        float4 o = {gelu_f(s.x + cp.x), gelu_f(s.y + cp.y), gelu_f(s.z + cp.z), gelu_f(s.w + cp.w)};
        *(float4*)&sB[w * LDS_STRIDE + t0] = o;
    }
    __syncthreads();

    // ---- 6. cge stage2: sB -> sA (var_claim)
    gemm_ks(sB, cge_w2, ks0, t0, acc);
    write_part(part, w, t0, acc);
    __syncthreads();
    {
        float4 s = reduce_part(part, w, t0);
        float4 bv = *(const float4*)&cge_b2[t0];
        float4 o = {gelu_f(s.x + bv.x), gelu_f(s.y + bv.y), gelu_f(s.z + bv.z), gelu_f(s.w + bv.w)};
        *(float4*)&sA[w * LDS_STRIDE + t0] = o;
    }
    __syncthreads();

    // ---- 7. cep fi: sA -> global
    gemm_ks(sA, cep_w1, ks0, t0, acc);
    write_part(part, w, t0, acc);
    __syncthreads();
    {
        float4 s = reduce_part(part, w, t0);
        float4 cp = *(const float4*)&ctxproj[(4 * 32 + b) * 256 + t0];
        float4 o = {s.x + cp.x, s.y + cp.y, s.z + cp.z, s.w + cp.w};
        *(float4*)&fi_cep[(b * 64 + n0 + w) * 256 + t0] = o;
    }
    __syncthreads();

    // ---- 8. cep fj: sA -> sB, then transpose to fjt_cep
    gemm_ks(sA, cep_w1 + 512 * 256, ks0, t0, acc);
    write_part(part, w, t0, acc);
    __syncthreads();
    {
        float4 s = reduce_part(part, w, t0);
        float4 cp = *(const float4*)&ctxproj[(5 * 32 + b) * 256 + t0];
        float4 o = {s.x + cp.x, s.y + cp.y, s.z + cp.z, s.w + cp.w};
        *(float4*)&sB[w * LDS_STRIDE + t0] = o;
    }
    __syncthreads();
    {
        int t = tid & 255, half = tid >> 8;
        float v0 = sB[(half * 4 + 0) * LDS_STRIDE + t];
        float v1 = sB[(half * 4 + 1) * LDS_STRIDE + t];
        float v2 = sB[(half * 4 + 2) * LDS_STRIDE + t];
        float v3 = sB[(half * 4 + 3) * LDS_STRIDE + t];
        float4 o = {v0, v1, v2, v3};
        *(float4*)&fjt_cep[(b * 256 + t) * 64 + n0 + half * 4] = o;
    }
}

// ---------------- K3: fused edge logits + entropy partials ----------------
__global__ __launch_bounds__(64) void k3_edges(
    const float* __restrict__ fi_dep, const float* __restrict__ fjt_dep,
    const float* __restrict__ fi_cep, const float* __restrict__ fjt_cep,
    const float* __restrict__ dep_w2, const float* __restrict__ dep_b2,
    const float* __restrict__ cep_w2, const float* __restrict__ cep_b2,
    float* __restrict__ Wd, float* __restrict__ Wc, float* __restrict__ entp)
{
    const int b = blockIdx.x >> 6;
    const int i = blockIdx.x & 63;
    const int j = threadIdx.x;

    const float4* fiD = (const float4*)(fi_dep + (b * 64 + i) * 256);
    const float4* fiC = (const float4*)(fi_cep + (b * 64 + i) * 256);
    const float*  fjD = fjt_dep + b * 256 * 64 + j;
    const float*  fjC = fjt_cep + b * 256 * 64 + j;
    const float4* w2D = (const float4*)dep_w2;
    const float4* w2C = (const float4*)cep_w2;

    float accD = 0.0f, accC = 0.0f;
    #pragma unroll 2
    for (int m = 0; m < 64; ++m) {
        float4 fd = fiD[m];
        float4 wd = w2D[m];
        int d0 = 4 * m;
        float g0 = fjD[(d0 + 0) * 64];
        float g1 = fjD[(d0 + 1) * 64];
        float g2 = fjD[(d0 + 2) * 64];
        float g3 = fjD[(d0 + 3) * 64];
        accD = fmaf(gelu_f(fd.x + g0), wd.x, accD);
        accD = fmaf(gelu_f(fd.y + g1), wd.y, accD);
        accD = fmaf(gelu_f(fd.z + g2), wd.z, accD);
        accD = fmaf(gelu_f(fd.w + g3), wd.w, accD);

        float4 fc = fiC[m];
        float4 wc = w2C[m];
        float h0 = fjC[(d0 + 0) * 64];
        float h1 = fjC[(d0 + 1) * 64];
        float h2 = fjC[(d0 + 2) * 64];
        float h3 = fjC[(d0 + 3) * 64];
        accC = fmaf(gelu_f(fc.x + h0), wc.x, accC);
        accC = fmaf(gelu_f(fc.y + h1), wc.y, accC);
        accC = fmaf(gelu_f(fc.z + h2), wc.z, accC);
        accC = fmaf(gelu_f(fc.w + h3), wc.w, accC);
    }
    float lD = accD + dep_b2[0];
    float lC = accC + cep_b2[0];
    if (j == i) { lD = -1e9f; lC = -1e9f; }
    Wd[(b * 64 + i) * 64 + j] = lD;
    Wc[(b * 64 + i) * 64 + j] = lC;

    float p = sigmoid_f(lD);
    float e = -(p * logf(p + 1e-8f) + (1.0f - p) * logf(1.0f - p + 1e-8f));
    #pragma unroll
    for (int off = 32; off; off >>= 1) e += __shfl_down(e, off);
    if (j == 0) entp[b * 64 + i] = e;
}

// ---------------- K6: gate + combine + expm ----------------
__global__ __launch_bounds__(256) void k6_gate_expm(
    const float* __restrict__ Wd, const float* __restrict__ Wc,
    const float* __restrict__ entp,
    const float* __restrict__ gw1, const float* __restrict__ gb1,
    const float* __restrict__ gw2, const float* __restrict__ gb2,
    const int* __restrict__ n_samples,
    float* __restrict__ out, float* __restrict__ traces)
{
    __shared__ float Xs[64 * 68];
    __shared__ float Rs[64 * 68];
    __shared__ float sgate;
    __shared__ float sent;
    __shared__ int ssexp;

    const int b = blockIdx.x;
    const int tid = threadIdx.x;

    if (tid == 0) {
        float s = 0.0f;
        for (int c = 0; c < 64; ++c) s += entp[b * 64 + c];
        sent = s / 4096.0f;
    }
    __syncthreads();
    if (tid < 64) {
        float ns = fminf((float)n_samples[0] / 1000.0f, 1.0f);
        float ccf = 0.5f;
        float pre = ns * gw1[tid] + ccf * gw1[64 + tid] + sent * gw1[128 + tid] + gb1[tid];
        float hid = gelu_f(pre) * gw2[tid];
        #pragma unroll
        for (int off = 32; off; off >>= 1) hid += __shfl_down(hid, off);
        if (tid == 0) sgate = sigmoid_f(hid + gb2[0]);
    }
    __syncthreads();
    const float g = sgate;

    for (int idx = tid; idx < 4096; idx += 256) {
        float d = Wd[b * 4096 + idx];
        float c = Wc[b * 4096 + idx];
        float post = g * d + (1.0f - g) * c;
        float s = sigmoid_f(post);
        out[b * 4096 + idx] = s;
        int ii = idx >> 6, jj = idx & 63;
        Xs[ii * 68 + jj] = s * s;
    }
    __syncthreads();

    if (tid < 64) {
        float cs = 0.0f;
        for (int r = 0; r < 64; ++r) cs += Xs[r * 68 + tid];
        #pragma unroll
        for (int off = 32; off; off >>= 1) cs = fmaxf(cs, __shfl_down(cs, off));
        if (tid == 0) {
            int se = 0;
            if (cs > 0.5f) se = (int)ceilf(log2f(cs * 2.0f));
            if (se < 0) se = 0;
            if (se > 12) se = 12;
            ssexp = se;
        }
    }
    __syncthreads();
    const int sexp = ssexp;
    const float scale = ldexpf(1.0f, -sexp);
    for (int idx = tid; idx < 4096; idx += 256) {
        Xs[(idx >> 6) * 68 + (idx & 63)] *= scale;
    }
    __syncthreads();

    for (int idx = tid; idx < 4096; idx += 256) {
        int ii = idx >> 6, jj = idx & 63;
        Rs[ii * 68 + jj] = Xs[ii * 68 + jj] * (1.0f / 14.0f) + ((ii == jj) ? 1.0f : 0.0f);
    }
    __syncthreads();

    const int rq = tid >> 4, cq = tid & 15;
    const int r0 = rq * 4, c0 = cq * 4;

    for (int k = 13; k >= 1; --k) {
        float acc[4][4];
        #pragma unroll
        for (int i = 0; i < 4; ++i)
            #pragma unroll
            for (int j = 0; j < 4; ++j) acc[i][j] = 0.0f;
        for (int kb = 0; kb < 64; kb += 4) {
            float4 xa[4];
            #pragma unroll
            for (int i = 0; i < 4; ++i) xa[i] = *(const float4*)&Xs[(r0 + i) * 68 + kb];
            #pragma unroll
            for (int kk = 0; kk < 4; ++kk) {
                float4 rv = *(const float4*)&Rs[(kb + kk) * 68 + c0];
                float rj[4] = {rv.x, rv.y, rv.z, rv.w};
                #pragma unroll
                for (int i = 0; i < 4; ++i) {
                    float xv = f4c(xa[i], kk);
                    #pragma unroll
                    for (int j = 0; j < 4; ++j) acc[i][j] = fmaf(xv, rj[j], acc[i][j]);
                }
            }
        }
        __syncthreads();
        float invk = 1.0f / (float)k;
        #pragma unroll
        for (int i = 0; i < 4; ++i)
            #pragma unroll
            for (int j = 0; j < 4; ++j)
                Rs[(r0 + i) * 68 + c0 + j] = acc[i][j] * invk + (((r0 + i) == (c0 + j)) ? 1.0f : 0.0f);
        __syncthreads();
    }

    for (int sq = 0; sq < sexp; ++sq) {
        double acc[4][4];
        #pragma unroll
        for (int i = 0; i < 4; ++i)
            #pragma unroll
            for (int j = 0; j < 4; ++j) acc[i][j] = 0.0;
        for (int kb = 0; kb < 64; kb += 4) {
            float4 xa[4];
            #pragma unroll
            for (int i = 0; i < 4; ++i) xa[i] = *(const float4*)&Rs[(r0 + i) * 68 + kb];
            #pragma unroll
            for (int kk = 0; kk < 4; ++kk) {
                float4 rv = *(const float4*)&Rs[(kb + kk) * 68 + c0];
                double rj[4] = {(double)rv.x, (double)rv.y, (double)rv.z, (double)rv.w};
                #pragma unroll
                for (int i = 0; i < 4; ++i) {
                    double xv = (double)f4c(xa[i], kk);
                    #pragma unroll
                    for (int j = 0; j < 4; ++j) acc[i][j] = fma(xv, rj[j], acc[i][j]);
                }
            }
        }
        __syncthreads();
        #pragma unroll
        for (int i = 0; i < 4; ++i)
            #pragma unroll
            for (int j = 0; j < 4; ++j)
                Rs[(r0 + i) * 68 + c0 + j] = (float)acc[i][j];
        __syncthreads();
    }

    if (tid == 0) {
        double tr = 0.0;
        for (int i = 0; i < 64; ++i) tr += (double)Rs[i * 68 + i];
        traces[b] = (float)tr;
    }
}

// ---------------- K7: acyc ----------------
__global__ void k7_acyc(const float* __restrict__ traces, float* __restrict__ out)
{
    if (threadIdx.x == 0 && blockIdx.x == 0) {
        double s = 0.0;
        for (int b = 0; b < 32; ++b) s += (double)traces[b];
        out[131072] = (float)(s / 32.0 - 64.0);
    }
}

extern "C" void kernel_launch(void* const* d_in, const int* in_sizes, int n_in,
                              void* d_out, int out_size, void* d_ws, size_t ws_size,
                              hipStream_t stream)
{
    (void)in_sizes; (void)n_in; (void)out_size; (void)ws_size;

    const float* ds     = (const float*)d_in[0];
    const float* ve     = (const float*)d_in[1];
    const float* cc     = (const float*)d_in[2];
    const float* dge_w1 = (const float*)d_in[3];
    const float* dge_b1 = (const float*)d_in[4];
    const float* dge_w2 = (const float*)d_in[5];
    const float* dge_b2 = (const float*)d_in[6];
    const float* cge_w1 = (const float*)d_in[7];
    const float* cge_b1 = (const float*)d_in[8];
    const float* cge_w2 = (const float*)d_in[9];
    const float* cge_b2 = (const float*)d_in[10];
    const float* dep_w1 = (const float*)d_in[11];
    const float* dep_b1 = (const float*)d_in[12];
    const float* dep_w2 = (const float*)d_in[13];
    const float* dep_b2 = (const float*)d_in[14];
    const float* cep_w1 = (const float*)d_in[15];
    const float* cep_b1 = (const float*)d_in[16];
    const float* cep_w2 = (const float*)d_in[17];
    const float* cep_b2 = (const float*)d_in[18];
    const float* gw1    = (const float*)d_in[19];
    const float* gb1    = (const float*)d_in[20];
    const float* gw2    = (const float*)d_in[21];
    const float* gb2    = (const float*)d_in[22];
    const int*   nsamp  = (const int*)d_in[23];

    float* ws = (float*)d_ws;
    float* ctxproj = ws;                       // 6*32*256   = 49152
    float* fi_dep  = ctxproj + 49152;          // 32*64*256  = 524288
    float* fjt_dep = fi_dep + 524288;          // 524288
    float* fi_cep  = fjt_dep + 524288;         // 524288
    float* fjt_cep = fi_cep + 524288;          // 524288
    float* Wd      = fjt_cep + 524288;         // 131072
    float* Wc      = Wd + 131072;              // 131072
    float* entp    = Wc + 131072;              // 2048
    float* traces  = entp + 2048;              // 32

    float* outp = (float*)d_out;

    k0_ctx<<<dim3(32, 6), 256, 0, stream>>>(ds, cc, dge_w1, dge_b1, cge_w1, cge_b1,
                                            dep_w1, dep_b1, cep_w1, cep_b1, ctxproj);
    k1_encode<<<256, 512, 0, stream>>>(ve, dge_w1, dge_w2, dge_b2,
                                       cge_w1, cge_w2, cge_b2,
                                       dep_w1, cep_w1, ctxproj,
                                       fi_dep, fjt_dep, fi_cep, fjt_cep);
    k3_edges<<<2048, 64, 0, stream>>>(fi_dep, fjt_dep, fi_cep, fjt_cep,
                                      dep_w2, dep_b2, cep_w2, cep_b2,
                                      Wd, Wc, entp);
    k6_gate_expm<<<32, 256, 0, stream>>>(Wd, Wc, entp, gw1, gb1, gw2, gb2,
                                         nsamp, outp, traces);
    k7_acyc<<<1, 64, 0, stream>>>(traces, outp);
}